// Round 5
// baseline (371.100 us; speedup 1.0000x reference)
//
#include <hip/hip_runtime.h>
#include <hip/hip_bf16.h>
#include <math.h>
#include <type_traits>

typedef __hip_bfloat16 bf16;
using short8  = __attribute__((ext_vector_type(8))) short;
using short4v = __attribute__((ext_vector_type(4))) short;
using f32x4   = __attribute__((ext_vector_type(4))) float;

#define TS 2048
#define TH 16
#define TD 64
#define TE 1024
#define T2E 2048

// async global->LDS, 16B per lane; lds base must be wave-uniform.
__device__ __forceinline__ void gload16(void* lds, const void* g) {
    __builtin_amdgcn_global_load_lds(
        (__attribute__((address_space(1))) void*)g,
        (__attribute__((address_space(3))) void*)lds, 16, 0, 0);
}

// truncating bf16x2 pack: a -> low16, b -> high16 (2 VALU ops, no RNE)
__device__ __forceinline__ uint32_t pktrunc(float a, float b) {
    return (__builtin_bit_cast(uint32_t, a) >> 16) |
           (__builtin_bit_cast(uint32_t, b) & 0xFFFF0000u);
}

// ---------------------------------------------------------------------------
// merged fp32 -> bf16 convert for all 5 tensors (one launch).
// ---------------------------------------------------------------------------
__global__ __launch_bounds__(256) void f2b_multi(
    const float* __restrict__ s0, bf16* __restrict__ d0,
    const float* __restrict__ s1, bf16* __restrict__ d1,
    const float* __restrict__ s2, bf16* __restrict__ d2,
    const float* __restrict__ s3, bf16* __restrict__ d3,
    const float* __restrict__ s4, bf16* __restrict__ d4)
{
    int blk = blockIdx.x;
    const float* s; bf16* d; int base;
    if (blk < 2048)      { s = s0; d = d0; base = 0; }
    else if (blk < 3584) { s = s1; d = d1; base = 2048; }
    else if (blk < 4096) { s = s2; d = d2; base = 3584; }
    else if (blk < 6144) { s = s3; d = d3; base = 4096; }
    else                 { s = s4; d = d4; base = 6144; }
    size_t i = ((size_t)(blk - base) * 256 + threadIdx.x) * 8;
    float4 a = *(const float4*)&s[i];
    float4 b = *(const float4*)&s[i + 4];
    bf16 t[8];
    t[0] = __float2bfloat16(a.x); t[1] = __float2bfloat16(a.y);
    t[2] = __float2bfloat16(a.z); t[3] = __float2bfloat16(a.w);
    t[4] = __float2bfloat16(b.x); t[5] = __float2bfloat16(b.y);
    t[6] = __float2bfloat16(b.z); t[7] = __float2bfloat16(b.w);
    *(uint4*)&d[i] = *(uint4*)t;
}

// ---------------------------------------------------------------------------
// gemm256: C[M,N] = A[M,K] @ B[N,K]^T (+bias, +GELU opt), 2-phase counted-vmcnt
// pipeline + T2 XOR-swizzled LDS (both-sides: linear global_load_lds dest,
// inverse-swizzled per-lane GLOBAL source, swizzled ds_read column).
// Tile 256 x BN (BN in {256,192}), 8 waves (2Mx4N), BK=64, double-buffered.
// ---------------------------------------------------------------------------
template <typename TC, bool GELU, bool QS, bool WVT, int BN>
__global__ __launch_bounds__(512, 2) void gemm256(
    const bf16* __restrict__ A, const bf16* __restrict__ Bw,
    const float* __restrict__ bias, TC* __restrict__ C,
    bf16* __restrict__ vTout, int M, int N, int K, int kLen, int Cstride)
{
    constexpr int NB = BN / 64;      // B-tile stage loads per thread
    constexpr int NI = BN / 64;      // N-frags per wave
    constexpr int WN = BN / 4;       // cols per wave
    __shared__ bf16 As[2][256 * 64];
    __shared__ bf16 Bs[2][BN * 64];

    const int t    = threadIdx.x;
    const int lane = t & 63;
    const int wv   = t >> 6;
    const int wr   = wv >> 2;        // 0..1
    const int wc   = wv & 3;         // 0..3
    const int lr   = lane & 15;
    const int lq   = lane >> 4;

    // XCD-aware bijective swizzle (nwg % 8 == 0 for all launches here)
    const int gx  = gridDim.x, gxy = gridDim.x * gridDim.y;
    const int nwg = gxy * gridDim.z;
    const int id  = blockIdx.x + gx * blockIdx.y + gxy * blockIdx.z;
    const int sid = (id & 7) * (nwg >> 3) + (id >> 3);
    const int zIdx  = sid / gxy;
    const int rem   = sid - zIdx * gxy;
    const int tm    = rem / gx;
    const int mBase = tm * 256;
    const int nBase = (rem - tm * gx) * BN;
    const int kOff  = zIdx * kLen;

    // stage addressing: row group r = t>>3; the 16B chunk each lane fetches
    // is XOR-swizzled by (row&7) so that LDS (written linearly by
    // global_load_lds) holds chunk s^(row&7) at slot s.
    const int sr = t >> 3;
    const int sc = (((t & 7) ^ ((t >> 3) & 7)) * 8);
    const int NT = kLen >> 6;

    const bf16* aPt = A  + (size_t)(mBase + sr) * K + sc;
    const bf16* bPt = Bw + (size_t)(nBase + sr) * K + sc;

    f32x4 acc[8][NI];
    #pragma unroll
    for (int mi = 0; mi < 8; mi++)
        #pragma unroll
        for (int ni = 0; ni < NI; ni++)
            acc[mi][ni] = (f32x4){0.f, 0.f, 0.f, 0.f};

    auto stage = [&](int b, int k0) {
        #pragma unroll
        for (int i = 0; i < 4; i++)
            gload16(&As[b][i * 4096 + wv * 512],
                    aPt + (size_t)(i * 64) * K + k0);
        #pragma unroll
        for (int i = 0; i < NB; i++)
            gload16(&Bs[b][i * 4096 + wv * 512],
                    bPt + (size_t)(i * 64) * K + k0);
    };

    stage(0, kOff);
    for (int kt = 0; kt < NT; ++kt) {
        const int cur = kt & 1;
        if (kt + 1 < NT) {
            stage(cur ^ 1, kOff + (kt + 1) * 64);
            // counted wait: current tile's loads done, next tile's in flight
            if constexpr (BN == 256)
                asm volatile("s_waitcnt vmcnt(8)" ::: "memory");
            else if constexpr (BN == 192)
                asm volatile("s_waitcnt vmcnt(7)" ::: "memory");
            else
                asm volatile("s_waitcnt vmcnt(6)" ::: "memory");
        } else {
            asm volatile("s_waitcnt vmcnt(0)" ::: "memory");
        }
        __builtin_amdgcn_s_barrier();
        asm volatile("" ::: "memory");

        short8 bfr[NI][2];
        #pragma unroll
        for (int ni = 0; ni < NI; ni++)
            #pragma unroll
            for (int ks = 0; ks < 2; ks++) {
                int row = wc * WN + ni * 16 + lr;
                int col = (ks * 32 + lq * 8) ^ ((lr & 7) * 8);
                bfr[ni][ks] = *(const short8*)&Bs[cur][row * 64 + col];
            }
        #pragma unroll
        for (int mi = 0; mi < 8; mi++) {
            int row = wr * 128 + mi * 16 + lr;
            int c0 = (lq * 8) ^ ((lr & 7) * 8);
            int c1 = (32 + lq * 8) ^ ((lr & 7) * 8);
            short8 a0 = *(const short8*)&As[cur][row * 64 + c0];
            short8 a1 = *(const short8*)&As[cur][row * 64 + c1];
            #pragma unroll
            for (int ni = 0; ni < NI; ni++) {
                acc[mi][ni] = __builtin_amdgcn_mfma_f32_16x16x32_bf16(
                    a0, bfr[ni][0], acc[mi][ni], 0, 0, 0);
                acc[mi][ni] = __builtin_amdgcn_mfma_f32_16x16x32_bf16(
                    a1, bfr[ni][1], acc[mi][ni], 0, 0, 0);
            }
        }
        // drain LDS reads before releasing the buffer to next tile's DMA
        asm volatile("s_waitcnt lgkmcnt(0)" ::: "memory");
        __builtin_amdgcn_s_barrier();
    }

    const size_t cOff = (size_t)zIdx * M * Cstride;
    #pragma unroll
    for (int mi = 0; mi < 8; mi++) {
        #pragma unroll
        for (int ni = 0; ni < NI; ni++) {
            int cc = nBase + wc * WN + ni * 16 + lr;
            float bv = (zIdx == 0) ? bias[cc] : 0.f;
            int r0 = mBase + wr * 128 + mi * 16 + lq * 4;
            bool vpath = false;
            if constexpr (WVT) {
                if (cc >= 2 * TE) {
                    vpath = true;
                    int d  = cc - 2 * TE;
                    int s0 = r0 & (TS - 1);
                    int bb = r0 >> 11;
                    int pos = (s0 & ~31) | (((s0 >> 2) & 3) << 3)
                            | (((s0 >> 4) & 1) << 2);
                    bf16 ob[4];
                    #pragma unroll
                    for (int i = 0; i < 4; i++)
                        ob[i] = __float2bfloat16(acc[mi][ni][i] + bv);
                    *(uint2*)&vTout[((size_t)(bb * TH + (d >> 6)) * TD + (d & 63))
                                    * TS + pos] = *(uint2*)ob;
                }
            }
            if (!vpath) {
                #pragma unroll
                for (int i = 0; i < 4; i++) {
                    float v = acc[mi][ni][i] + bv;
                    if constexpr (GELU)
                        v = 0.5f * v * (1.0f + erff(v * 0.70710678118f));
                    if constexpr (QS)
                        if (cc < TE) v *= 0.180336880111f;   // 0.125 * log2(e)
                    if constexpr (std::is_same_v<TC, bf16>)
                        C[cOff + (size_t)(r0 + i) * Cstride + cc] = __float2bfloat16(v);
                    else
                        C[cOff + (size_t)(r0 + i) * Cstride + cc] = v;
                }
            }
        }
    }
}

// ---------------------------------------------------------------------------
// gemm128n: C[M,N] = A[M,K] @ B[N,K]^T (+bias), fp32 out. Tile 128x256,
// 8 waves (2Mx4N, 64x64 per wave), BK=64, 3-buffer LDS ring with stage
// distance TWO tiles ahead (deeper counted-vmcnt pipeline: gate vmcnt(12)
// keeps 2 tiles = 12 loads in flight; tail 6 then 0). Same T2 XOR swizzle
// as gemm256. Used for the split-K GEMMs (out-proj, FC2).
// ---------------------------------------------------------------------------
__global__ __launch_bounds__(512, 2) void gemm128n(
    const bf16* __restrict__ A, const bf16* __restrict__ Bw,
    const float* __restrict__ bias, float* __restrict__ C,
    int M, int N, int K, int kLen)
{
    __shared__ bf16 As[3][128 * 64];   // 3 x 16 KiB
    __shared__ bf16 Bs[3][256 * 64];   // 3 x 32 KiB  (total 144 KiB)

    const int t    = threadIdx.x;
    const int lane = t & 63;
    const int wv   = t >> 6;
    const int wr   = wv >> 2;        // 0..1 -> 64-row strip
    const int wc   = wv & 3;         // 0..3 -> 64-col strip
    const int lr   = lane & 15;
    const int lq   = lane >> 4;

    const int gx  = gridDim.x, gxy = gridDim.x * gridDim.y;
    const int nwg = gxy * gridDim.z;
    const int id  = blockIdx.x + gx * blockIdx.y + gxy * blockIdx.z;
    const int sid = (id & 7) * (nwg >> 3) + (id >> 3);
    const int zIdx  = sid / gxy;
    const int rem   = sid - zIdx * gxy;
    const int tm    = rem / gx;
    const int mBase = tm * 128;
    const int nBase = (rem - tm * gx) * 256;
    const int kOff  = zIdx * kLen;

    const int sr = t >> 3;
    const int sc = (((t & 7) ^ ((t >> 3) & 7)) * 8);

    const bf16* aPt = A  + (size_t)(mBase + sr) * K + sc;
    const bf16* bPt = Bw + (size_t)(nBase + sr) * K + sc;

    f32x4 acc[4][4];
    #pragma unroll
    for (int mi = 0; mi < 4; mi++)
        #pragma unroll
        for (int ni = 0; ni < 4; ni++)
            acc[mi][ni] = (f32x4){0.f, 0.f, 0.f, 0.f};

    // 6 loads per tile: A 2 (128 rows), B 4 (256 rows)
    auto stage = [&](int b, int k0) {
        #pragma unroll
        for (int i = 0; i < 2; i++)
            gload16(&As[b][i * 4096 + wv * 512],
                    aPt + (size_t)(i * 64) * K + k0);
        #pragma unroll
        for (int i = 0; i < 4; i++)
            gload16(&Bs[b][i * 4096 + wv * 512],
                    bPt + (size_t)(i * 64) * K + k0);
    };

    const int NT = kLen >> 6;        // >= 8 for all uses
    stage(0, kOff);
    stage(1, kOff + 64);
    int cur = 0;
    for (int kt = 0; kt < NT; ++kt) {
        if (kt + 2 < NT) {
            int nb = cur + 2; if (nb >= 3) nb -= 3;
            stage(nb, kOff + (kt + 2) * 64);
            // tile kt complete; tiles kt+1, kt+2 (12 loads) stay in flight
            asm volatile("s_waitcnt vmcnt(12)" ::: "memory");
        } else if (kt + 1 < NT) {
            asm volatile("s_waitcnt vmcnt(6)" ::: "memory");
        } else {
            asm volatile("s_waitcnt vmcnt(0)" ::: "memory");
        }
        __builtin_amdgcn_s_barrier();
        asm volatile("" ::: "memory");

        short8 af[4][2], bfr[4][2];
        #pragma unroll
        for (int mi = 0; mi < 4; mi++)
            #pragma unroll
            for (int ks = 0; ks < 2; ks++) {
                int row = wr * 64 + mi * 16 + lr;
                int col = (ks * 32 + lq * 8) ^ ((lr & 7) * 8);
                af[mi][ks] = *(const short8*)&As[cur][row * 64 + col];
            }
        #pragma unroll
        for (int ni = 0; ni < 4; ni++)
            #pragma unroll
            for (int ks = 0; ks < 2; ks++) {
                int row = wc * 64 + ni * 16 + lr;
                int col = (ks * 32 + lq * 8) ^ ((lr & 7) * 8);
                bfr[ni][ks] = *(const short8*)&Bs[cur][row * 64 + col];
            }
        #pragma unroll
        for (int mi = 0; mi < 4; mi++)
            #pragma unroll
            for (int ni = 0; ni < 4; ni++) {
                acc[mi][ni] = __builtin_amdgcn_mfma_f32_16x16x32_bf16(
                    af[mi][0], bfr[ni][0], acc[mi][ni], 0, 0, 0);
                acc[mi][ni] = __builtin_amdgcn_mfma_f32_16x16x32_bf16(
                    af[mi][1], bfr[ni][1], acc[mi][ni], 0, 0, 0);
            }
        asm volatile("s_waitcnt lgkmcnt(0)" ::: "memory");
        __builtin_amdgcn_s_barrier();
        cur += 1; if (cur >= 3) cur = 0;
    }

    const size_t cOff = (size_t)zIdx * M * N;
    #pragma unroll
    for (int mi = 0; mi < 4; mi++) {
        #pragma unroll
        for (int ni = 0; ni < 4; ni++) {
            int cc = nBase + wc * 64 + ni * 16 + lr;
            float bv = (zIdx == 0) ? bias[cc] : 0.f;
            int r0 = mBase + wr * 64 + mi * 16 + lq * 4;
            #pragma unroll
            for (int i = 0; i < 4; i++)
                C[cOff + (size_t)(r0 + i) * N + cc] = acc[mi][ni][i] + bv;
        }
    }
}

// ---------------------------------------------------------------------------
// Flash attention v6: 8-wave blocks, QBLK=128 q-rows per block (K/V tiles are
// q-independent, so same 35.8KB LDS now feeds 2x the q-rows: total staging
// instructions halved and occupancy doubles to 4 blocks x 8 waves = 32
// waves/CU). S^T = mfma(K-frag, Q-frag) -> P^T feeds PV from regs.
// Q,K read from packed qk buffer (stride T2E=2048). V key-permuted (gemm WVT)
// so PV reads Vt as b128. Truncating bf16 packs; no clamp (logits |s|<~4).
// ---------------------------------------------------------------------------
__global__ __launch_bounds__(512, 8) void attn_flash(
    const bf16* __restrict__ qkv, const bf16* __restrict__ vT,
    bf16* __restrict__ attnO)
{
    __shared__ bf16 Ks[128 * 72];    // 18432 B
    __shared__ bf16 Vt[64 * 136];    // 17408 B

    const int t    = threadIdx.x;
    const int lane = t & 63;
    const int wv   = t >> 6;        // 0..7
    const int c    = lane & 15;     // q column (S^T) / d-row (PV)
    const int u    = lane >> 4;     // quad
    const int bid  = blockIdx.x;
    const int bh   = (bid & 7) * 4 + ((bid >> 3) & 3);   // same head -> same XCD
    const int qt   = bid >> 5;      // 0..15 (128 q-rows per block)
    const int h = bh & 15, b = bh >> 4;
    const size_t tokBase = (size_t)b * TS;
    const int qrow = qt * 128 + wv * 16 + c;

    // Q fragment (pre-scaled by 0.125*log2e in QKV epilogue)
    short8 qf[2];
    #pragma unroll
    for (int kc = 0; kc < 2; kc++)
        qf[kc] = *(const short8*)&qkv[(tokBase + qrow) * T2E + h * TD + kc * 32 + u * 8];

    f32x4 oacc[4];
    #pragma unroll
    for (int di = 0; di < 4; di++) oacc[di] = (f32x4){0.f, 0.f, 0.f, 0.f};
    float lsum = 0.f;

    for (int it = 0; it < 16; it++) {
        const int kb0 = it * 128;
        __syncthreads();             // prev iter's Ks/Vt reads complete

        // stage K-block [128 keys][64 d] -> Ks (stride 72); 512 thr x 2 chunks
        #pragma unroll
        for (int i = 0; i < 2; i++) {
            int l = t + i * 512;
            int r = l >> 3, ch = (l & 7) * 8;
            *(uint4*)&Ks[r * 72 + ch] =
                *(const uint4*)&qkv[(tokBase + kb0 + r) * T2E + TE + h * TD + ch];
        }
        // stage V^T block [64 d][128 pos] -> Vt (stride 136); key-permuted,
        // contiguous from vT; 512 thr x 2 chunks
        #pragma unroll
        for (int i = 0; i < 2; i++) {
            int c0 = t + i * 512;
            int vd = c0 >> 4, vcc = (c0 & 15) * 8;
            *(uint4*)&Vt[vd * 136 + vcc] =
                *(const uint4*)&vT[((size_t)bh * TD + vd) * TS + kb0 + vcc];
        }
        __syncthreads();             // stage complete

        // S^T[key][q] = sum_d K[key][d] Q[q][d]
        f32x4 sacc[8];
        #pragma unroll
        for (int kc = 0; kc < 2; kc++) {
            #pragma unroll
            for (int kb = 0; kb < 8; kb++) {
                short8 kf = *(const short8*)&Ks[(kb * 16 + c) * 72 + kc * 32 + u * 8];
                sacc[kb] = __builtin_amdgcn_mfma_f32_16x16x32_bf16(
                    kf, qf[kc],
                    kc == 0 ? (f32x4){0.f, 0.f, 0.f, 0.f} : sacc[kb], 0, 0, 0);
            }
        }

        // per 32-key group: exp2 -> trunc-pack P^T B-frags -> PV (b128 Vt reads)
        #pragma unroll
        for (int p = 0; p < 4; p++) {
            union { uint32_t d[2]; short4v s; } pb0, pb1;
            {
                float a0 = exp2f(sacc[2*p][0]);
                float a1 = exp2f(sacc[2*p][1]);
                float a2 = exp2f(sacc[2*p][2]);
                float a3 = exp2f(sacc[2*p][3]);
                float b0 = exp2f(sacc[2*p+1][0]);
                float b1 = exp2f(sacc[2*p+1][1]);
                float b2 = exp2f(sacc[2*p+1][2]);
                float b3 = exp2f(sacc[2*p+1][3]);
                lsum += (a0 + a1) + (a2 + a3) + (b0 + b1) + (b2 + b3);
                pb0.d[0] = pktrunc(a0, a1); pb0.d[1] = pktrunc(a2, a3);
                pb1.d[0] = pktrunc(b0, b1); pb1.d[1] = pktrunc(b2, b3);
            }
            #pragma unroll
            for (int di = 0; di < 4; di++) {
                short8 vv = *(const short8*)&Vt[(di * 16 + c) * 136 + p * 32 + u * 8];
                short4v lo = __builtin_shufflevector(vv, vv, 0, 1, 2, 3);
                short4v hi = __builtin_shufflevector(vv, vv, 4, 5, 6, 7);
                oacc[di] = __builtin_amdgcn_mfma_f32_16x16x16bf16_1k(
                    lo, pb0.s, oacc[di], 0, 0, 0);
                oacc[di] = __builtin_amdgcn_mfma_f32_16x16x16bf16_1k(
                    hi, pb1.s, oacc[di], 0, 0, 0);
            }
        }
    }

    // l: reduce across quads (lanes with same q-col)
    lsum += __shfl_xor(lsum, 16, 64);
    lsum += __shfl_xor(lsum, 32, 64);
    const float inv = 1.0f / lsum;

    // O^T lane holds q=c, d = di*16 + u*4 + rg -> 8B packed stores
    #pragma unroll
    for (int di = 0; di < 4; di++) {
        bf16 ob[4];
        #pragma unroll
        for (int rg = 0; rg < 4; rg++)
            ob[rg] = __float2bfloat16(oacc[di][rg] * inv);
        *(uint2*)&attnO[(tokBase + qrow) * TE + h * TD + di * 16 + u * 4] = *(uint2*)ob;
    }
}

// ---------------------------------------------------------------------------
// out = LayerNorm(a + p0 + p1) * g + beta; optional bf16 copy.
// ---------------------------------------------------------------------------
__global__ __launch_bounds__(256) void add_ln3(
    const float* __restrict__ a, const float* __restrict__ p0,
    const float* __restrict__ p1, const float* __restrict__ g,
    const float* __restrict__ beta, float* __restrict__ out,
    bf16* __restrict__ outb)
{
    __shared__ float r1[256], r2[256];
    const int t = threadIdx.x;
    const size_t row = (size_t)blockIdx.x * TE;

    float4 va = *(const float4*)&a[row + t * 4];
    float4 v0 = *(const float4*)&p0[row + t * 4];
    float4 v1 = *(const float4*)&p1[row + t * 4];
    float v[4] = {va.x + v0.x + v1.x, va.y + v0.y + v1.y,
                  va.z + v0.z + v1.z, va.w + v0.w + v1.w};
    float s = 0.f, s2 = 0.f;
    #pragma unroll
    for (int i = 0; i < 4; i++) { s += v[i]; s2 += v[i] * v[i]; }
    r1[t] = s; r2[t] = s2;
    __syncthreads();
    for (int off = 128; off > 0; off >>= 1) {
        if (t < off) { r1[t] += r1[t + off]; r2[t] += r2[t + off]; }
        __syncthreads();
    }
    const float mu  = r1[0] * (1.f / 1024.f);
    const float var = r2[0] * (1.f / 1024.f) - mu * mu;
    const float rs  = rsqrtf(var + 1e-5f);
    float4 vg  = *(const float4*)&g[t * 4];
    float4 vbt = *(const float4*)&beta[t * 4];
    float o[4];
    o[0] = (v[0] - mu) * rs * vg.x + vbt.x;
    o[1] = (v[1] - mu) * rs * vg.y + vbt.y;
    o[2] = (v[2] - mu) * rs * vg.z + vbt.z;
    o[3] = (v[3] - mu) * rs * vg.w + vbt.w;
    *(float4*)&out[row + t * 4] = *(float4*)o;
    if (outb) {
        bf16 ob[4];
        #pragma unroll
        for (int i = 0; i < 4; i++) ob[i] = __float2bfloat16(o[i]);
        *(uint2*)&outb[row + t * 4] = *(uint2*)ob;
    }
}

// ---------------------------------------------------------------------------
extern "C" void kernel_launch(void* const* d_in, const int* in_sizes, int n_in,
                              void* d_out, int out_size, void* d_ws, size_t ws_size,
                              hipStream_t stream)
{
    const float* x     = (const float*)d_in[0];
    const float* w_qkv = (const float*)d_in[1];
    const float* b_qkv = (const float*)d_in[2];
    const float* w_out = (const float*)d_in[3];
    const float* b_out = (const float*)d_in[4];
    const float* g1    = (const float*)d_in[5];
    const float* beta1 = (const float*)d_in[6];
    const float* w_fc1 = (const float*)d_in[7];
    const float* b_fc1 = (const float*)d_in[8];
    const float* w_fc2 = (const float*)d_in[9];
    const float* b_fc2 = (const float*)d_in[10];
    const float* g2    = (const float*)d_in[11];
    const float* beta2 = (const float*)d_in[12];
    float* out = (float*)d_out;

    // workspace layout (byte offsets), 120 MiB peak (timeline-safe aliasing):
    //  [0,16M)   : qk bf16 packed QK (steps 1-2)         -> y0 / ff0 fp32
    //  [16M,24M) : vT bf16 (steps 1-2)                   -> y1 / ff1 (cont.)
    //  [24M,32M) : xb bf16 (steps 0-1)                   -> (y/ff tail)
    //  [0,32M)   : y fp32 2 partials (3-4), ff 2 partials (6-7)
    //  [32M,40M) : attnO bf16 (2-3)                      -> x1b bf16 (4-5)
    //  [40M,48M) : wfc1b
    //  [48M,50M) : woutb
    //  [50M,56M) : wqkvb
    //  [64M,80M) : x1 fp32 (4-7)
    //  [80M,112M): hbuf bf16 (5-6)
    //  [112M,120M): wfc2b
    char* wsb   = (char*)d_ws;
    bf16*  qk    = (bf16*)(wsb);
    bf16*  vT    = (bf16*)(wsb + 16777216);
    bf16*  xb    = (bf16*)(wsb + 25165824);
    float* y     = (float*)(wsb);
    float* ff    = (float*)(wsb);
    bf16*  attnO = (bf16*)(wsb + 33554432);
    bf16*  x1b   = (bf16*)(wsb + 33554432);
    bf16*  wfc1b = (bf16*)(wsb + 41943040);
    bf16*  woutb = (bf16*)(wsb + 50331648);
    bf16*  wqkvb = (bf16*)(wsb + 52428800);
    float* x1    = (float*)(wsb + 67108864);
    bf16*  hbuf  = (bf16*)(wsb + 83886080);
    bf16*  wfc2b = (bf16*)(wsb + 117440512);

    const int M = 2 * TS;
    const size_t PART = (size_t)M * TE;
    dim3 blk(256), blk8(512);

    // 0) all fp32->bf16 converts in one launch
    f2b_multi<<<dim3(8192), blk, 0, stream>>>(
        x, xb, w_qkv, wqkvb, w_out, woutb, w_fc1, wfc1b, w_fc2, wfc2b);

    // 1) QK(+bias, Q pre-scaled) packed at stride 2048; V permuted to vT
    //    BN=192: grid 16x16 = 256 blocks = exactly 1/CU
    gemm256<bf16, false, true, true, 192><<<dim3(16, 16, 1), blk8, 0, stream>>>(
        xb, wqkvb, b_qkv, qk, vT, M, 3072, TE, TE, T2E);
    // 2) flash attention (128 q-rows/block, 512 blocks, 8 waves, XCD-swizzled)
    attn_flash<<<dim3(512), blk8, 0, stream>>>(qk, vT, attnO);
    // 3) y{0,1} = attnO @ woutb^T (+b_out), split-K=2, 128x256 tiles, 3-ring
    gemm128n<<<dim3(4, 32, 2), blk8, 0, stream>>>(
        attnO, woutb, b_out, y, M, TE, TE, TE / 2);
    // 4) x1 = LN(x + y0 + y1); also x1b
    add_ln3<<<dim3(M), blk, 0, stream>>>(x, y, y + PART, g1, beta1, x1, x1b);
    // 5) hbuf = gelu(x1b @ wfc1b^T + b_fc1), 256x256 tiles
    gemm256<bf16, true, false, false, 256><<<dim3(16, 16, 1), blk8, 0, stream>>>(
        x1b, wfc1b, b_fc1, hbuf, nullptr, M, 4096, TE, TE, 4096);
    // 6) ff{0,1} = hbuf @ wfc2b^T (+b_fc2), split-K=2, 128x256 tiles, 3-ring
    gemm128n<<<dim3(4, 32, 2), blk8, 0, stream>>>(
        hbuf, wfc2b, b_fc2, ff, M, TE, 4096, 2048);
    // 7) out = LN(x1 + ff0 + ff1)
    add_ln3<<<dim3(M), blk, 0, stream>>>(x1, ff, ff + PART, g2, beta2, out, nullptr);
}

// Round 6
// 355.012 us; speedup vs baseline: 1.0453x; 1.0453x over previous
//
#include <hip/hip_runtime.h>
#include <hip/hip_bf16.h>
#include <math.h>
#include <type_traits>

typedef __hip_bfloat16 bf16;
using short8  = __attribute__((ext_vector_type(8))) short;
using short4v = __attribute__((ext_vector_type(4))) short;
using f32x4   = __attribute__((ext_vector_type(4))) float;

#define TS 2048
#define TH 16
#define TD 64
#define TE 1024
#define T2E 2048

// async global->LDS, 16B per lane; lds base must be wave-uniform.
__device__ __forceinline__ void gload16(void* lds, const void* g) {
    __builtin_amdgcn_global_load_lds(
        (__attribute__((address_space(1))) void*)g,
        (__attribute__((address_space(3))) void*)lds, 16, 0, 0);
}

// truncating bf16x2 pack: a -> low16, b -> high16 (2 VALU ops, no RNE)
__device__ __forceinline__ uint32_t pktrunc(float a, float b) {
    return (__builtin_bit_cast(uint32_t, a) >> 16) |
           (__builtin_bit_cast(uint32_t, b) & 0xFFFF0000u);
}

// ---------------------------------------------------------------------------
// merged fp32 -> bf16 convert for all 5 tensors (one launch).
// ---------------------------------------------------------------------------
__global__ __launch_bounds__(256) void f2b_multi(
    const float* __restrict__ s0, bf16* __restrict__ d0,
    const float* __restrict__ s1, bf16* __restrict__ d1,
    const float* __restrict__ s2, bf16* __restrict__ d2,
    const float* __restrict__ s3, bf16* __restrict__ d3,
    const float* __restrict__ s4, bf16* __restrict__ d4)
{
    int blk = blockIdx.x;
    const float* s; bf16* d; int base;
    if (blk < 2048)      { s = s0; d = d0; base = 0; }
    else if (blk < 3584) { s = s1; d = d1; base = 2048; }
    else if (blk < 4096) { s = s2; d = d2; base = 3584; }
    else if (blk < 6144) { s = s3; d = d3; base = 4096; }
    else                 { s = s4; d = d4; base = 6144; }
    size_t i = ((size_t)(blk - base) * 256 + threadIdx.x) * 8;
    float4 a = *(const float4*)&s[i];
    float4 b = *(const float4*)&s[i + 4];
    bf16 t[8];
    t[0] = __float2bfloat16(a.x); t[1] = __float2bfloat16(a.y);
    t[2] = __float2bfloat16(a.z); t[3] = __float2bfloat16(a.w);
    t[4] = __float2bfloat16(b.x); t[5] = __float2bfloat16(b.y);
    t[6] = __float2bfloat16(b.z); t[7] = __float2bfloat16(b.w);
    *(uint4*)&d[i] = *(uint4*)t;
}

// ---------------------------------------------------------------------------
// gemm256: C[M,N] = A[M,K] @ B[N,K]^T (+bias, +GELU opt), 2-phase counted-vmcnt
// pipeline + T2 XOR-swizzled LDS (both-sides: linear global_load_lds dest,
// inverse-swizzled per-lane GLOBAL source, swizzled ds_read column).
// Tile 256 x BN (BN in {256,192}), 8 waves (2Mx4N), BK=64, double-buffered.
// ---------------------------------------------------------------------------
template <typename TC, bool GELU, bool QS, bool WVT, int BN>
__global__ __launch_bounds__(512, 2) void gemm256(
    const bf16* __restrict__ A, const bf16* __restrict__ Bw,
    const float* __restrict__ bias, TC* __restrict__ C,
    bf16* __restrict__ vTout, int M, int N, int K, int kLen, int Cstride)
{
    constexpr int NB = BN / 64;      // B-tile stage loads per thread
    constexpr int NI = BN / 64;      // N-frags per wave
    constexpr int WN = BN / 4;       // cols per wave
    __shared__ bf16 As[2][256 * 64];
    __shared__ bf16 Bs[2][BN * 64];

    const int t    = threadIdx.x;
    const int lane = t & 63;
    const int wv   = t >> 6;
    const int wr   = wv >> 2;        // 0..1
    const int wc   = wv & 3;         // 0..3
    const int lr   = lane & 15;
    const int lq   = lane >> 4;

    // XCD-aware bijective swizzle (nwg % 8 == 0 for all launches here)
    const int gx  = gridDim.x, gxy = gridDim.x * gridDim.y;
    const int nwg = gxy * gridDim.z;
    const int id  = blockIdx.x + gx * blockIdx.y + gxy * blockIdx.z;
    const int sid = (id & 7) * (nwg >> 3) + (id >> 3);
    const int zIdx  = sid / gxy;
    const int rem   = sid - zIdx * gxy;
    const int tm    = rem / gx;
    const int mBase = tm * 256;
    const int nBase = (rem - tm * gx) * BN;
    const int kOff  = zIdx * kLen;

    // stage addressing: row group r = t>>3; the 16B chunk each lane fetches
    // is XOR-swizzled by (row&7) so that LDS (written linearly by
    // global_load_lds) holds chunk s^(row&7) at slot s.
    const int sr = t >> 3;
    const int sc = (((t & 7) ^ ((t >> 3) & 7)) * 8);
    const int NT = kLen >> 6;

    const bf16* aPt = A  + (size_t)(mBase + sr) * K + sc;
    const bf16* bPt = Bw + (size_t)(nBase + sr) * K + sc;

    f32x4 acc[8][NI];
    #pragma unroll
    for (int mi = 0; mi < 8; mi++)
        #pragma unroll
        for (int ni = 0; ni < NI; ni++)
            acc[mi][ni] = (f32x4){0.f, 0.f, 0.f, 0.f};

    auto stage = [&](int b, int k0) {
        #pragma unroll
        for (int i = 0; i < 4; i++)
            gload16(&As[b][i * 4096 + wv * 512],
                    aPt + (size_t)(i * 64) * K + k0);
        #pragma unroll
        for (int i = 0; i < NB; i++)
            gload16(&Bs[b][i * 4096 + wv * 512],
                    bPt + (size_t)(i * 64) * K + k0);
    };

    stage(0, kOff);
    for (int kt = 0; kt < NT; ++kt) {
        const int cur = kt & 1;
        if (kt + 1 < NT) {
            stage(cur ^ 1, kOff + (kt + 1) * 64);
            // counted wait: current tile's loads done, next tile's in flight
            if constexpr (BN == 256)
                asm volatile("s_waitcnt vmcnt(8)" ::: "memory");
            else if constexpr (BN == 192)
                asm volatile("s_waitcnt vmcnt(7)" ::: "memory");
            else
                asm volatile("s_waitcnt vmcnt(6)" ::: "memory");
        } else {
            asm volatile("s_waitcnt vmcnt(0)" ::: "memory");
        }
        __builtin_amdgcn_s_barrier();
        asm volatile("" ::: "memory");

        short8 bfr[NI][2];
        #pragma unroll
        for (int ni = 0; ni < NI; ni++)
            #pragma unroll
            for (int ks = 0; ks < 2; ks++) {
                int row = wc * WN + ni * 16 + lr;
                int col = (ks * 32 + lq * 8) ^ ((lr & 7) * 8);
                bfr[ni][ks] = *(const short8*)&Bs[cur][row * 64 + col];
            }
        #pragma unroll
        for (int mi = 0; mi < 8; mi++) {
            int row = wr * 128 + mi * 16 + lr;
            int c0 = (lq * 8) ^ ((lr & 7) * 8);
            int c1 = (32 + lq * 8) ^ ((lr & 7) * 8);
            short8 a0 = *(const short8*)&As[cur][row * 64 + c0];
            short8 a1 = *(const short8*)&As[cur][row * 64 + c1];
            #pragma unroll
            for (int ni = 0; ni < NI; ni++) {
                acc[mi][ni] = __builtin_amdgcn_mfma_f32_16x16x32_bf16(
                    a0, bfr[ni][0], acc[mi][ni], 0, 0, 0);
                acc[mi][ni] = __builtin_amdgcn_mfma_f32_16x16x32_bf16(
                    a1, bfr[ni][1], acc[mi][ni], 0, 0, 0);
            }
        }
        // drain LDS reads before releasing the buffer to next tile's DMA
        asm volatile("s_waitcnt lgkmcnt(0)" ::: "memory");
        __builtin_amdgcn_s_barrier();
    }

    const size_t cOff = (size_t)zIdx * M * Cstride;
    #pragma unroll
    for (int mi = 0; mi < 8; mi++) {
        #pragma unroll
        for (int ni = 0; ni < NI; ni++) {
            int cc = nBase + wc * WN + ni * 16 + lr;
            float bv = (zIdx == 0) ? bias[cc] : 0.f;
            int r0 = mBase + wr * 128 + mi * 16 + lq * 4;
            bool vpath = false;
            if constexpr (WVT) {
                if (cc >= 2 * TE) {
                    vpath = true;
                    int d  = cc - 2 * TE;
                    int s0 = r0 & (TS - 1);
                    int bb = r0 >> 11;
                    int pos = (s0 & ~31) | (((s0 >> 2) & 3) << 3)
                            | (((s0 >> 4) & 1) << 2);
                    bf16 ob[4];
                    #pragma unroll
                    for (int i = 0; i < 4; i++)
                        ob[i] = __float2bfloat16(acc[mi][ni][i] + bv);
                    *(uint2*)&vTout[((size_t)(bb * TH + (d >> 6)) * TD + (d & 63))
                                    * TS + pos] = *(uint2*)ob;
                }
            }
            if (!vpath) {
                #pragma unroll
                for (int i = 0; i < 4; i++) {
                    float v = acc[mi][ni][i] + bv;
                    if constexpr (GELU)
                        v = 0.5f * v * (1.0f + erff(v * 0.70710678118f));
                    if constexpr (QS)
                        if (cc < TE) v *= 0.180336880111f;   // 0.125 * log2(e)
                    if constexpr (std::is_same_v<TC, bf16>)
                        C[cOff + (size_t)(r0 + i) * Cstride + cc] = __float2bfloat16(v);
                    else
                        C[cOff + (size_t)(r0 + i) * Cstride + cc] = v;
                }
            }
        }
    }
}

// ---------------------------------------------------------------------------
// gemm128n: C[M,N] = A[M,K] @ B[N,K]^T (+bias), fp32 out. Tile 128x256,
// 8 waves (2Mx4N, 64x64 per wave), BK=64, 3-buffer LDS ring with stage
// distance TWO tiles ahead (deeper counted-vmcnt pipeline: gate vmcnt(12)
// keeps 2 tiles = 12 loads in flight; tail 6 then 0). Same T2 XOR swizzle
// as gemm256. Used for the split-K GEMMs (out-proj, FC2).
// ---------------------------------------------------------------------------
__global__ __launch_bounds__(512, 2) void gemm128n(
    const bf16* __restrict__ A, const bf16* __restrict__ Bw,
    const float* __restrict__ bias, float* __restrict__ C,
    int M, int N, int K, int kLen)
{
    __shared__ bf16 As[3][128 * 64];   // 3 x 16 KiB
    __shared__ bf16 Bs[3][256 * 64];   // 3 x 32 KiB  (total 144 KiB)

    const int t    = threadIdx.x;
    const int lane = t & 63;
    const int wv   = t >> 6;
    const int wr   = wv >> 2;        // 0..1 -> 64-row strip
    const int wc   = wv & 3;         // 0..3 -> 64-col strip
    const int lr   = lane & 15;
    const int lq   = lane >> 4;

    const int gx  = gridDim.x, gxy = gridDim.x * gridDim.y;
    const int nwg = gxy * gridDim.z;
    const int id  = blockIdx.x + gx * blockIdx.y + gxy * blockIdx.z;
    const int sid = (id & 7) * (nwg >> 3) + (id >> 3);
    const int zIdx  = sid / gxy;
    const int rem   = sid - zIdx * gxy;
    const int tm    = rem / gx;
    const int mBase = tm * 128;
    const int nBase = (rem - tm * gx) * 256;
    const int kOff  = zIdx * kLen;

    const int sr = t >> 3;
    const int sc = (((t & 7) ^ ((t >> 3) & 7)) * 8);

    const bf16* aPt = A  + (size_t)(mBase + sr) * K + sc;
    const bf16* bPt = Bw + (size_t)(nBase + sr) * K + sc;

    f32x4 acc[4][4];
    #pragma unroll
    for (int mi = 0; mi < 4; mi++)
        #pragma unroll
        for (int ni = 0; ni < 4; ni++)
            acc[mi][ni] = (f32x4){0.f, 0.f, 0.f, 0.f};

    // 6 loads per tile: A 2 (128 rows), B 4 (256 rows)
    auto stage = [&](int b, int k0) {
        #pragma unroll
        for (int i = 0; i < 2; i++)
            gload16(&As[b][i * 4096 + wv * 512],
                    aPt + (size_t)(i * 64) * K + k0);
        #pragma unroll
        for (int i = 0; i < 4; i++)
            gload16(&Bs[b][i * 4096 + wv * 512],
                    bPt + (size_t)(i * 64) * K + k0);
    };

    const int NT = kLen >> 6;        // >= 8 for all uses
    stage(0, kOff);
    stage(1, kOff + 64);
    int cur = 0;
    for (int kt = 0; kt < NT; ++kt) {
        if (kt + 2 < NT) {
            int nb = cur + 2; if (nb >= 3) nb -= 3;
            stage(nb, kOff + (kt + 2) * 64);
            // tile kt complete; tiles kt+1, kt+2 (12 loads) stay in flight
            asm volatile("s_waitcnt vmcnt(12)" ::: "memory");
        } else if (kt + 1 < NT) {
            asm volatile("s_waitcnt vmcnt(6)" ::: "memory");
        } else {
            asm volatile("s_waitcnt vmcnt(0)" ::: "memory");
        }
        __builtin_amdgcn_s_barrier();
        asm volatile("" ::: "memory");

        short8 af[4][2], bfr[4][2];
        #pragma unroll
        for (int mi = 0; mi < 4; mi++)
            #pragma unroll
            for (int ks = 0; ks < 2; ks++) {
                int row = wr * 64 + mi * 16 + lr;
                int col = (ks * 32 + lq * 8) ^ ((lr & 7) * 8);
                af[mi][ks] = *(const short8*)&As[cur][row * 64 + col];
            }
        #pragma unroll
        for (int ni = 0; ni < 4; ni++)
            #pragma unroll
            for (int ks = 0; ks < 2; ks++) {
                int row = wc * 64 + ni * 16 + lr;
                int col = (ks * 32 + lq * 8) ^ ((lr & 7) * 8);
                bfr[ni][ks] = *(const short8*)&Bs[cur][row * 64 + col];
            }
        #pragma unroll
        for (int mi = 0; mi < 4; mi++)
            #pragma unroll
            for (int ni = 0; ni < 4; ni++) {
                acc[mi][ni] = __builtin_amdgcn_mfma_f32_16x16x32_bf16(
                    af[mi][0], bfr[ni][0], acc[mi][ni], 0, 0, 0);
                acc[mi][ni] = __builtin_amdgcn_mfma_f32_16x16x32_bf16(
                    af[mi][1], bfr[ni][1], acc[mi][ni], 0, 0, 0);
            }
        asm volatile("s_waitcnt lgkmcnt(0)" ::: "memory");
        __builtin_amdgcn_s_barrier();
        cur += 1; if (cur >= 3) cur = 0;
    }

    const size_t cOff = (size_t)zIdx * M * N;
    #pragma unroll
    for (int mi = 0; mi < 4; mi++) {
        #pragma unroll
        for (int ni = 0; ni < 4; ni++) {
            int cc = nBase + wc * 64 + ni * 16 + lr;
            float bv = (zIdx == 0) ? bias[cc] : 0.f;
            int r0 = mBase + wr * 64 + mi * 16 + lq * 4;
            #pragma unroll
            for (int i = 0; i < 4; i++)
                C[cOff + (size_t)(r0 + i) * N + cc] = acc[mi][ni][i] + bv;
        }
    }
}

// ---------------------------------------------------------------------------
// Flash attention v6b: 8-wave blocks, QBLK=128 q-rows per block (K/V tiles
// are q-independent, so same 35.8KB LDS feeds 2x the q-rows: total staging
// instructions and L2 staging traffic halved vs QBLK=64). launch_bounds
// (512,4): 128-VGPR budget -- round 5's (512,8) forced a 64-VGPR budget,
// spilled sacc to scratch (VGPR_Count=32, WRITE_SIZE 8->48MB). 2 blocks/CU
// x 8 waves = 16 waves/CU cap (same as QBLK=64 config, at half the staging).
// ---------------------------------------------------------------------------
__global__ __launch_bounds__(512, 4) void attn_flash(
    const bf16* __restrict__ qkv, const bf16* __restrict__ vT,
    bf16* __restrict__ attnO)
{
    __shared__ bf16 Ks[128 * 72];    // 18432 B
    __shared__ bf16 Vt[64 * 136];    // 17408 B

    const int t    = threadIdx.x;
    const int lane = t & 63;
    const int wv   = t >> 6;        // 0..7
    const int c    = lane & 15;     // q column (S^T) / d-row (PV)
    const int u    = lane >> 4;     // quad
    const int bid  = blockIdx.x;
    const int bh   = (bid & 7) * 4 + ((bid >> 3) & 3);   // same head -> same XCD
    const int qt   = bid >> 5;      // 0..15 (128 q-rows per block)
    const int h = bh & 15, b = bh >> 4;
    const size_t tokBase = (size_t)b * TS;
    const int qrow = qt * 128 + wv * 16 + c;

    // Q fragment (pre-scaled by 0.125*log2e in QKV epilogue)
    short8 qf[2];
    #pragma unroll
    for (int kc = 0; kc < 2; kc++)
        qf[kc] = *(const short8*)&qkv[(tokBase + qrow) * T2E + h * TD + kc * 32 + u * 8];

    f32x4 oacc[4];
    #pragma unroll
    for (int di = 0; di < 4; di++) oacc[di] = (f32x4){0.f, 0.f, 0.f, 0.f};
    float lsum = 0.f;

    for (int it = 0; it < 16; it++) {
        const int kb0 = it * 128;
        __syncthreads();             // prev iter's Ks/Vt reads complete

        // stage K-block [128 keys][64 d] -> Ks (stride 72); 512 thr x 2 chunks
        #pragma unroll
        for (int i = 0; i < 2; i++) {
            int l = t + i * 512;
            int r = l >> 3, ch = (l & 7) * 8;
            *(uint4*)&Ks[r * 72 + ch] =
                *(const uint4*)&qkv[(tokBase + kb0 + r) * T2E + TE + h * TD + ch];
        }
        // stage V^T block [64 d][128 pos] -> Vt (stride 136); key-permuted,
        // contiguous from vT; 512 thr x 2 chunks
        #pragma unroll
        for (int i = 0; i < 2; i++) {
            int c0 = t + i * 512;
            int vd = c0 >> 4, vcc = (c0 & 15) * 8;
            *(uint4*)&Vt[vd * 136 + vcc] =
                *(const uint4*)&vT[((size_t)bh * TD + vd) * TS + kb0 + vcc];
        }
        __syncthreads();             // stage complete

        // S^T[key][q] = sum_d K[key][d] Q[q][d]
        f32x4 sacc[8];
        #pragma unroll
        for (int kc = 0; kc < 2; kc++) {
            #pragma unroll
            for (int kb = 0; kb < 8; kb++) {
                short8 kf = *(const short8*)&Ks[(kb * 16 + c) * 72 + kc * 32 + u * 8];
                sacc[kb] = __builtin_amdgcn_mfma_f32_16x16x32_bf16(
                    kf, qf[kc],
                    kc == 0 ? (f32x4){0.f, 0.f, 0.f, 0.f} : sacc[kb], 0, 0, 0);
            }
        }

        // per 32-key group: exp2 -> trunc-pack P^T B-frags -> PV (b128 Vt reads)
        #pragma unroll
        for (int p = 0; p < 4; p++) {
            union { uint32_t d[2]; short4v s; } pb0, pb1;
            {
                float a0 = exp2f(sacc[2*p][0]);
                float a1 = exp2f(sacc[2*p][1]);
                float a2 = exp2f(sacc[2*p][2]);
                float a3 = exp2f(sacc[2*p][3]);
                float b0 = exp2f(sacc[2*p+1][0]);
                float b1 = exp2f(sacc[2*p+1][1]);
                float b2 = exp2f(sacc[2*p+1][2]);
                float b3 = exp2f(sacc[2*p+1][3]);
                lsum += (a0 + a1) + (a2 + a3) + (b0 + b1) + (b2 + b3);
                pb0.d[0] = pktrunc(a0, a1); pb0.d[1] = pktrunc(a2, a3);
                pb1.d[0] = pktrunc(b0, b1); pb1.d[1] = pktrunc(b2, b3);
            }
            #pragma unroll
            for (int di = 0; di < 4; di++) {
                short8 vv = *(const short8*)&Vt[(di * 16 + c) * 136 + p * 32 + u * 8];
                short4v lo = __builtin_shufflevector(vv, vv, 0, 1, 2, 3);
                short4v hi = __builtin_shufflevector(vv, vv, 4, 5, 6, 7);
                oacc[di] = __builtin_amdgcn_mfma_f32_16x16x16bf16_1k(
                    lo, pb0.s, oacc[di], 0, 0, 0);
                oacc[di] = __builtin_amdgcn_mfma_f32_16x16x16bf16_1k(
                    hi, pb1.s, oacc[di], 0, 0, 0);
            }
        }
    }

    // l: reduce across quads (lanes with same q-col)
    lsum += __shfl_xor(lsum, 16, 64);
    lsum += __shfl_xor(lsum, 32, 64);
    const float inv = 1.0f / lsum;

    // O^T lane holds q=c, d = di*16 + u*4 + rg -> 8B packed stores
    #pragma unroll
    for (int di = 0; di < 4; di++) {
        bf16 ob[4];
        #pragma unroll
        for (int rg = 0; rg < 4; rg++)
            ob[rg] = __float2bfloat16(oacc[di][rg] * inv);
        *(uint2*)&attnO[(tokBase + qrow) * TE + h * TD + di * 16 + u * 4] = *(uint2*)ob;
    }
}

// ---------------------------------------------------------------------------
// out = LayerNorm(a + p0 + p1) * g + beta; optional bf16 copy.
// ---------------------------------------------------------------------------
__global__ __launch_bounds__(256) void add_ln3(
    const float* __restrict__ a, const float* __restrict__ p0,
    const float* __restrict__ p1, const float* __restrict__ g,
    const float* __restrict__ beta, float* __restrict__ out,
    bf16* __restrict__ outb)
{
    __shared__ float r1[256], r2[256];
    const int t = threadIdx.x;
    const size_t row = (size_t)blockIdx.x * TE;

    float4 va = *(const float4*)&a[row + t * 4];
    float4 v0 = *(const float4*)&p0[row + t * 4];
    float4 v1 = *(const float4*)&p1[row + t * 4];
    float v[4] = {va.x + v0.x + v1.x, va.y + v0.y + v1.y,
                  va.z + v0.z + v1.z, va.w + v0.w + v1.w};
    float s = 0.f, s2 = 0.f;
    #pragma unroll
    for (int i = 0; i < 4; i++) { s += v[i]; s2 += v[i] * v[i]; }
    r1[t] = s; r2[t] = s2;
    __syncthreads();
    for (int off = 128; off > 0; off >>= 1) {
        if (t < off) { r1[t] += r1[t + off]; r2[t] += r2[t + off]; }
        __syncthreads();
    }
    const float mu  = r1[0] * (1.f / 1024.f);
    const float var = r2[0] * (1.f / 1024.f) - mu * mu;
    const float rs  = rsqrtf(var + 1e-5f);
    float4 vg  = *(const float4*)&g[t * 4];
    float4 vbt = *(const float4*)&beta[t * 4];
    float o[4];
    o[0] = (v[0] - mu) * rs * vg.x + vbt.x;
    o[1] = (v[1] - mu) * rs * vg.y + vbt.y;
    o[2] = (v[2] - mu) * rs * vg.z + vbt.z;
    o[3] = (v[3] - mu) * rs * vg.w + vbt.w;
    *(float4*)&out[row + t * 4] = *(float4*)o;
    if (outb) {
        bf16 ob[4];
        #pragma unroll
        for (int i = 0; i < 4; i++) ob[i] = __float2bfloat16(o[i]);
        *(uint2*)&outb[row + t * 4] = *(uint2*)ob;
    }
}

// ---------------------------------------------------------------------------
extern "C" void kernel_launch(void* const* d_in, const int* in_sizes, int n_in,
                              void* d_out, int out_size, void* d_ws, size_t ws_size,
                              hipStream_t stream)
{
    const float* x     = (const float*)d_in[0];
    const float* w_qkv = (const float*)d_in[1];
    const float* b_qkv = (const float*)d_in[2];
    const float* w_out = (const float*)d_in[3];
    const float* b_out = (const float*)d_in[4];
    const float* g1    = (const float*)d_in[5];
    const float* beta1 = (const float*)d_in[6];
    const float* w_fc1 = (const float*)d_in[7];
    const float* b_fc1 = (const float*)d_in[8];
    const float* w_fc2 = (const float*)d_in[9];
    const float* b_fc2 = (const float*)d_in[10];
    const float* g2    = (const float*)d_in[11];
    const float* beta2 = (const float*)d_in[12];
    float* out = (float*)d_out;

    // workspace layout (byte offsets), 120 MiB peak (timeline-safe aliasing):
    //  [0,16M)   : qk bf16 packed QK (steps 1-2)         -> y0 / ff0 fp32
    //  [16M,24M) : vT bf16 (steps 1-2)                   -> y1 / ff1 (cont.)
    //  [24M,32M) : xb bf16 (steps 0-1)                   -> (y/ff tail)
    //  [0,32M)   : y fp32 2 partials (3-4), ff 2 partials (6-7)
    //  [32M,40M) : attnO bf16 (2-3)                      -> x1b bf16 (4-5)
    //  [40M,48M) : wfc1b
    //  [48M,50M) : woutb
    //  [50M,56M) : wqkvb
    //  [64M,80M) : x1 fp32 (4-7)
    //  [80M,112M): hbuf bf16 (5-6)
    //  [112M,120M): wfc2b
    char* wsb   = (char*)d_ws;
    bf16*  qk    = (bf16*)(wsb);
    bf16*  vT    = (bf16*)(wsb + 16777216);
    bf16*  xb    = (bf16*)(wsb + 25165824);
    float* y     = (float*)(wsb);
    float* ff    = (float*)(wsb);
    bf16*  attnO = (bf16*)(wsb + 33554432);
    bf16*  x1b   = (bf16*)(wsb + 33554432);
    bf16*  wfc1b = (bf16*)(wsb + 41943040);
    bf16*  woutb = (bf16*)(wsb + 50331648);
    bf16*  wqkvb = (bf16*)(wsb + 52428800);
    float* x1    = (float*)(wsb + 67108864);
    bf16*  hbuf  = (bf16*)(wsb + 83886080);
    bf16*  wfc2b = (bf16*)(wsb + 117440512);

    const int M = 2 * TS;
    const size_t PART = (size_t)M * TE;
    dim3 blk(256), blk8(512);

    // 0) all fp32->bf16 converts in one launch
    f2b_multi<<<dim3(8192), blk, 0, stream>>>(
        x, xb, w_qkv, wqkvb, w_out, woutb, w_fc1, wfc1b, w_fc2, wfc2b);

    // 1) QK(+bias, Q pre-scaled) packed at stride 2048; V permuted to vT
    //    BN=192: grid 16x16 = 256 blocks = exactly 1/CU
    gemm256<bf16, false, true, true, 192><<<dim3(16, 16, 1), blk8, 0, stream>>>(
        xb, wqkvb, b_qkv, qk, vT, M, 3072, TE, TE, T2E);
    // 2) flash attention (128 q-rows/block, 512 blocks, 8 waves, XCD-swizzled)
    attn_flash<<<dim3(512), blk8, 0, stream>>>(qk, vT, attnO);
    // 3) y{0,1} = attnO @ woutb^T (+b_out), split-K=2, 128x256 tiles, 3-ring
    gemm128n<<<dim3(4, 32, 2), blk8, 0, stream>>>(
        attnO, woutb, b_out, y, M, TE, TE, TE / 2);
    // 4) x1 = LN(x + y0 + y1); also x1b
    add_ln3<<<dim3(M), blk, 0, stream>>>(x, y, y + PART, g1, beta1, x1, x1b);
    // 5) hbuf = gelu(x1b @ wfc1b^T + b_fc1), 256x256 tiles
    gemm256<bf16, true, false, false, 256><<<dim3(16, 16, 1), blk8, 0, stream>>>(
        x1b, wfc1b, b_fc1, hbuf, nullptr, M, 4096, TE, TE, 4096);
    // 6) ff{0,1} = hbuf @ wfc2b^T (+b_fc2), split-K=2, 128x256 tiles, 3-ring
    gemm128n<<<dim3(4, 32, 2), blk8, 0, stream>>>(
        hbuf, wfc2b, b_fc2, ff, M, TE, 4096, 2048);
    // 7) out = LN(x1 + ff0 + ff1)
    add_ln3<<<dim3(M), blk, 0, stream>>>(x1, ff, ff + PART, g2, beta2, out, nullptr);
}